// Round 8
// baseline (68.998 us; speedup 1.0000x reference)
//
#include <hip/hip_runtime.h>
#include <math.h>

// Tropical max/min-plus pseudo-matmul.
// out[b,u] = max_f(x[b,f] + w[f,u]) for u<128, min_f otherwise.
//
// R20: FORCE x onto the scalar pipe with inline-asm s_load_dwordx4.
// R19 post-mortem: AS4-pointer hint gave only -0.28us vs R12 -> the backend
// almost certainly still emitted VMEM broadcasts for x; VMEM (2048 x-bcast +
// 1024 w = ~12K cyc/CU) co-saturates with VALU (12.3K cyc/SIMD) -> ~10.5us
// kernel, the R17 arithmetic unchanged. Counters can't show SGPR_Count (the
// kernel is under the top-5 cutoff), so this round forces the selection:
//   - x loaded via asm "s_load_dwordx4 %0,%1,%2" with "=s" f32x4 outputs
//     (the proven SRSRC-style constraint), double-buffered: 2x8 quads =
//     64 SGPRs (~86/102 total). x tile = 16KB/CU -> scalar-cache resident.
//   - SMEM returns are OUT-OF-ORDER -> only lgkmcnt(0) is a valid wait.
//     Pipeline keeps exactly one batch outstanding at each wait:
//       issue B -> compute A (96 VALU ~ 192cyc covers K$ latency) ->
//       SB(0) -> s_waitcnt lgkmcnt(0) -> SB(0) -> compute B
//     The sched_barrier(0) pair is rule-#18: reg-only VALU crosses a
//     "memory" clobber, so without the fences compute-A could sink below
//     the wait (losing cover) or compute-B hoist above it (racing the load).
//   - w stays compiler-managed VMEM (float2, 512B/instr coalesced):
//     w-only VMEM ~ 3.4us/CU, L2 demand ~21.8TB/s (63% of ceiling), both
//     under the 5.1us VALU floor -- three separate pipes now.
// Geometry unchanged from R19: 16 waves (8 kslices x 2 halves), KW=64,
// 2 units/lane, wave-half min/max split (no divergence, no sign math),
// TLP=4 waves/SIMD, 96KB LDS belt -> 1 block/CU, epilogue tree in LDS.

#define FEAT  512
#define UNITS 256
#define BR    8            // rows per block
#define NW    16           // waves per block (8 k-slices x 2 halves)
#define KW    64           // k per wave
#define NS    (KW / 4)     // 16 steps, 4 k per step
#define LDSZ  24576        // 96KB declared (occupancy belt); 64KB used

typedef float f32x4 __attribute__((ext_vector_type(4)));

__device__ __forceinline__ float max3f(float a, float b, float c) {
    return fmaxf(fmaxf(a, b), c);   // v_max3_f32
}
__device__ __forceinline__ float min3f(float a, float b, float c) {
    return fminf(fminf(a, b), c);   // v_min3_f32
}

// one s_load_dwordx4 at compile-time byte offset OFF (template -> guaranteed imm)
template<int OFF>
__device__ __forceinline__ void sload1(const float* __restrict__ p, f32x4& d) {
    asm volatile("s_load_dwordx4 %0, %1, %2" : "=s"(d) : "s"(p), "i"(OFF));
}

// 8 s_load_dwordx4: x[row0+r][k0..k0+3], r=0..7 (byte offsets r*2048).
// Results NOT ready until s_waitcnt lgkmcnt(0).
__device__ __forceinline__ void sload_xstep(const float* __restrict__ xp_s,
                                            f32x4* __restrict__ xb) {
    sload1<0 * 2048>(xp_s, xb[0]);
    sload1<1 * 2048>(xp_s, xb[1]);
    sload1<2 * 2048>(xp_s, xb[2]);
    sload1<3 * 2048>(xp_s, xb[3]);
    sload1<4 * 2048>(xp_s, xb[4]);
    sload1<5 * 2048>(xp_s, xb[5]);
    sload1<6 * 2048>(xp_s, xb[6]);
    sload1<7 * 2048>(xp_s, xb[7]);
}

__device__ __forceinline__ void smem_wait_fenced() {
    __builtin_amdgcn_sched_barrier(0);                 // pin cover-compute above
    asm volatile("s_waitcnt lgkmcnt(0)" ::: "memory"); // SMEM is OOO: only 0 valid
    __builtin_amdgcn_sched_barrier(0);                 // pin consumers below
}

// 4 dwordx2: w[k0+j][u0..u0+1] -- 64 lanes x 8B = 512B contiguous
__device__ __forceinline__ void load_wstep(const float* __restrict__ wp, int s,
                                           float2* __restrict__ wb) {
    #pragma unroll
    for (int j = 0; j < 4; ++j)
        wb[j] = *(const float2*)(wp + (size_t)(s * 4 + j) * UNITS);
}

// per step: 8 rows x (8 add + 4 max3/min3) = 96 VALU inst; x from SGPRs
// (v_add_f32 v,s,v -- exactly one SGPR operand per instruction)
template<bool ISMAX>
__device__ __forceinline__ void compute_step(const f32x4* __restrict__ xb,
                                             const float2* __restrict__ wq,
                                             float2* __restrict__ acc) {
    #pragma unroll
    for (int r = 0; r < BR; ++r) {
        const f32x4 a = xb[r];
        const float t0x = a.x + wq[0].x, t0y = a.x + wq[0].y;
        const float t1x = a.y + wq[1].x, t1y = a.y + wq[1].y;
        const float t2x = a.z + wq[2].x, t2y = a.z + wq[2].y;
        const float t3x = a.w + wq[3].x, t3y = a.w + wq[3].y;
        float2 A = acc[r];
        if (ISMAX) {
            A.x = max3f(A.x, t0x, t1x);  A.x = max3f(A.x, t2x, t3x);
            A.y = max3f(A.y, t0y, t1y);  A.y = max3f(A.y, t2y, t3y);
        } else {
            A.x = min3f(A.x, t0x, t1x);  A.x = min3f(A.x, t2x, t3x);
            A.y = min3f(A.y, t0y, t1y);  A.y = min3f(A.y, t2y, t3y);
        }
        acc[r] = A;
    }
}

// software pipeline: x (SMEM) and w (VMEM) one step ahead; one SMEM batch
// outstanding at each wait
template<bool ISMAX>
__device__ __forceinline__ void main_loop(const float* __restrict__ xp,
                                          const float* __restrict__ wp,
                                          float2* __restrict__ acc) {
    f32x4  xA[BR], xB[BR];
    float2 wA[4], wB[4];
    sload_xstep(xp, xA);
    load_wstep(wp, 0, wA);
    smem_wait_fenced();                       // batch 0 ready
    #pragma unroll 1
    for (int s = 0; s < NS; s += 2) {
        sload_xstep(xp + (s + 1) * 4, xB);    // issue batch s+1
        load_wstep(wp, s + 1, wB);
        compute_step<ISMAX>(xA, wA, acc);     // covers batch s+1 latency
        smem_wait_fenced();                   // batch s+1 ready
        if (s + 2 < NS) {
            sload_xstep(xp + (s + 2) * 4, xA);
            load_wstep(wp, s + 2, wA);
        }
        compute_step<ISMAX>(xB, wB, acc);     // covers batch s+2 latency
        smem_wait_fenced();                   // batch s+2 ready (tail: no-op)
    }
}

__global__ __launch_bounds__(1024)
__attribute__((amdgpu_waves_per_eu(4, 4)))
void tropical_kernel(const float* __restrict__ x,
                     const float* __restrict__ w,
                     float* __restrict__ out) {
    __shared__ float lds[LDSZ];   // 96KB declared (belt); 64KB used
    const int tid  = threadIdx.x;
    const int lane = tid & 63;
    const int wv   = __builtin_amdgcn_readfirstlane(tid >> 6);  // 0..15
    const int kslice = wv & 7;           // k origin index
    const int half   = wv >> 3;          // 0: max units 0-127, 1: min 128-255
    const int ks   = kslice * KW;
    const int u0   = lane * 2;           // 2 units per lane, contiguous
    const int row0 = blockIdx.x * BR;

    const float* xp = x + (size_t)row0 * FEAT + ks;          // uniform
    const float* wp = w + (size_t)ks * UNITS + half * 128 + u0;

    float2 acc[BR];
    const float init = half ? __builtin_inff() : -__builtin_inff();
    #pragma unroll
    for (int r = 0; r < BR; ++r)
        acc[r] = make_float2(init, init);

    if (half == 0) main_loop<true >(xp, wp, acc);
    else           main_loop<false>(xp, wp, acc);

    // ---- partials to LDS: wave wv -> slot wv, 128 units of its half ----
    #pragma unroll
    for (int r = 0; r < BR; ++r)
        *(float2*)&lds[(wv * BR + r) * 128 + u0] = acc[r];   // 512B/wave-row
    __syncthreads();   // the kernel's only barrier

    // ---- combine 8 k-slice partials; thread -> float2 of output ----
    const int r  = tid >> 7;             // 0..7
    const int j2 = tid & 127;
    const int hh = j2 >> 6;              // wave-uniform: 0=max half, 1=min half
    const int uo = (j2 & 63) * 2;        // unit offset within the half
    float2 v = *(const float2*)&lds[((hh * 8 + 0) * BR + r) * 128 + uo];
    #pragma unroll
    for (int j = 1; j < 8; ++j) {
        const float2 p = *(const float2*)&lds[((hh * 8 + j) * BR + r) * 128 + uo];
        if (hh == 0) { v.x = fmaxf(v.x, p.x); v.y = fmaxf(v.y, p.y); }
        else         { v.x = fminf(v.x, p.x); v.y = fminf(v.y, p.y); }
    }
    *(float2*)&out[(size_t)(row0 + r) * UNITS + hh * 128 + uo] = v;
}

extern "C" void kernel_launch(void* const* d_in, const int* in_sizes, int n_in,
                              void* d_out, int out_size, void* d_ws, size_t ws_size,
                              hipStream_t stream) {
    const float* x = (const float*)d_in[0];   // (2048, 512)
    const float* w = (const float*)d_in[1];   // (512, 256)
    float* out = (float*)d_out;               // (2048, 256)

    // 256 blocks x 16 waves = 1 block/CU, 4 waves/SIMD
    tropical_kernel<<<dim3(2048 / BR), dim3(1024), 0, stream>>>(x, w, out);
}